// Round 7
// baseline (642.457 us; speedup 1.0000x reference)
//
#include <hip/hip_runtime.h>
#include <hip/hip_cooperative_groups.h>
#include <hip/hip_bf16.h>
#include <math.h>

namespace cg = cooperative_groups;

// N = 100000, E = 3.2M, F_in = 128, H = C = 16. int inputs arrive as int32.
//
// out[d] = dinv[d]*(sum_{s->d} u[s] + u[d]) + b,  u = dinv .* (h @ W).
// R3: global atomics ~19.5G txn/s -> 3.2M int atomics = ~16us (the old
//     "unusable" verdict was for 51M f32 message atomics).
// R6-R18: sort->CSR->register-gather pipeline, 221.8us best:
//   R13 uint2 lanes 234 / R16 8 nodes-wave 230.9 / R17 uint4 lanes 224.3 /
//   R18 xw1 4-out/thread 221.8. R14/R15/R19 regressed.
// R19 (coop fusion) REGRESSED 367us BUT exposed prep cost: ~150-172us of
//     the 221.8 is the 5-kernel radix+LDS-sort chain (VALU 2%, HBM 6% -
//     pure latency/serialization, ~5 memory touches per edge).
// R20: REPLACE prep algorithm with direct counting-sort CSR:
//     zero deg -> global-atomic deg histogram -> cooperative scan
//     (rowptr/cur/dinv) -> one-pass scatter sorted[atomic cursor]=src.
//     ~2.5 touches/edge, no LDS sort, no packed[] intermediate.
//     sorted[] holds plain src (<2^17 so gather's &0x1FFFF is identity).
//     Row order within a node is atomic-arbitrary: sums commute, OK.

#define F_IN 128
#define H 16
#define PFD 3              // prefetch depth: 16 slots * 3 = 48 edges/node
#define NPW 8              // nodes per wave
#define NPBLK 32           // nodes per block = 4 waves * NPW
#define SCB 98             // scan blocks: 98*1024 >= N

typedef __hip_bfloat16 bf16;

__device__ __forceinline__ float bflo(unsigned v) { return __uint_as_float(v << 16); }
__device__ __forceinline__ float bfhi(unsigned v) { return __uint_as_float(v & 0xffff0000u); }

// ---- prep 1: zero the degree array ----
__global__ void zero_kernel(int* __restrict__ deg, int N) {
    int i = blockIdx.x * blockDim.x + threadIdx.x;
    if (i < N) deg[i] = 0;
}

// ---- prep 2: degree histogram via global atomics (int4 reads) ----
__global__ void deg_kernel(const int* __restrict__ dst, int* __restrict__ deg, int E) {
    int i = blockIdx.x * blockDim.x + threadIdx.x;
    int stride = gridDim.x * blockDim.x;
    int E4 = E >> 2;
    const int4* d4 = (const int4*)dst;
    for (int e = i; e < E4; e += stride) {
        int4 v = d4[e];
        atomicAdd(&deg[v.x], 1);
        atomicAdd(&deg[v.y], 1);
        atomicAdd(&deg[v.z], 1);
        atomicAdd(&deg[v.w], 1);
    }
    for (int e = (E4 << 2) + i; e < E; e += stride)
        atomicAdd(&deg[dst[e]], 1);
}

// ---- prep 3: cooperative exclusive scan deg -> rowptr, cur, dinv ----
__global__ void __launch_bounds__(1024, 1)
scan_kernel(const int* __restrict__ deg, int* __restrict__ rowptr,
            int* __restrict__ cur, float* __restrict__ dinv,
            int* __restrict__ btot, int N, int E) {
    cg::grid_group grid = cg::this_grid();
    __shared__ int s[1024];
    int i = blockIdx.x * 1024 + threadIdx.x;
    int v = (i < N) ? deg[i] : 0;
    s[threadIdx.x] = v;
    __syncthreads();
    for (int off = 1; off < 1024; off <<= 1) {
        int w = (threadIdx.x >= off) ? s[threadIdx.x - off] : 0;
        __syncthreads();
        s[threadIdx.x] += w;
        __syncthreads();
    }
    int incl = s[threadIdx.x];
    if (threadIdx.x == 1023) btot[blockIdx.x] = incl;

    grid.sync();

    if (blockIdx.x == 0) {
        int t = threadIdx.x;
        int bv = (t < SCB) ? btot[t] : 0;
        s[t] = bv;
        __syncthreads();
        for (int off = 1; off < 1024; off <<= 1) {
            int w = (t >= off) ? s[t - off] : 0;
            __syncthreads();
            s[t] += w;
            __syncthreads();
        }
        if (t < SCB) btot[t] = s[t] - bv;   // exclusive block offset
    }

    grid.sync();

    int start = btot[blockIdx.x] + incl - v;   // exclusive prefix of element i
    if (i < N) {
        rowptr[i] = start;
        cur[i] = start;
        dinv[i] = rsqrtf(1.0f + (float)v);
    }
    if (i == 0) rowptr[N] = E;
}

// ---- prep 4: one-pass scatter to final CSR position ----
__global__ void scatter_kernel(const int* __restrict__ src, const int* __restrict__ dst,
                               int* __restrict__ cur, unsigned* __restrict__ sorted, int E) {
    int i = blockIdx.x * blockDim.x + threadIdx.x;
    int stride = gridDim.x * blockDim.x;
    int E4 = E >> 2;
    const int4* s4 = (const int4*)src;
    const int4* d4 = (const int4*)dst;
    for (int e = i; e < E4; e += stride) {
        int4 sv = s4[e];
        int4 dv = d4[e];
        int p0 = atomicAdd(&cur[dv.x], 1);
        int p1 = atomicAdd(&cur[dv.y], 1);
        int p2 = atomicAdd(&cur[dv.z], 1);
        int p3 = atomicAdd(&cur[dv.w], 1);
        sorted[p0] = (unsigned)sv.x;
        sorted[p1] = (unsigned)sv.y;
        sorted[p2] = (unsigned)sv.z;
        sorted[p3] = (unsigned)sv.w;
    }
    for (int e = (E4 << 2) + i; e < E; e += stride) {
        int p = atomicAdd(&cur[dst[e]], 1);
        sorted[p] = (unsigned)src[e];
    }
}

// ---- u[i][j] = dinv[i] * sum_k x[i][k]*W1[k][j]  (bf16 out) ----
// R18: 4 outputs per thread. lane = (row r: tid>>2) x (jq: tid&3 -> 4 ch).
#define XR 64
#define XPAD 132
__global__ void xw1_kernel(const float* __restrict__ x, const float* __restrict__ W1,
                           const float* __restrict__ dinv, bf16* __restrict__ u, int n) {
    __shared__ float sW1[F_IN * H];        // 8 KB, [k*16 + j]
    __shared__ float sx[XR * XPAD];        // 33.8 KB
    for (int t = threadIdx.x; t < F_IN * H; t += 256) sW1[t] = W1[t];

    int basei = blockIdx.x * XR;
    for (int idx = threadIdx.x; idx < XR * 32; idx += 256) {
        int r = idx >> 5;                  // 0..63
        int kk = (idx & 31) << 2;          // 0,4,...,124
        int row = basei + r;
        float4 v = make_float4(0.f, 0.f, 0.f, 0.f);
        if (row < n) v = *(const float4*)(x + (size_t)row * F_IN + kk);
        *(float4*)(sx + r * XPAD + kk) = v;
    }
    __syncthreads();

    int r = threadIdx.x >> 2;              // 0..63
    int jq = (threadIdx.x & 3) << 2;       // 0,4,8,12
    int row = basei + r;
    if (row >= n) return;

    const float* xr = sx + r * XPAD;
    float a0 = 0.f, a1 = 0.f, a2 = 0.f, a3 = 0.f;
#pragma unroll 16
    for (int k = 0; k < F_IN; k++) {
        float xk = xr[k];
        float4 w = *(const float4*)(sW1 + k * H + jq);
        a0 += xk * w.x; a1 += xk * w.y; a2 += xk * w.z; a3 += xk * w.w;
    }
    float di = dinv[row];
    bf16 b0 = __float2bfloat16(di * a0);
    bf16 b1 = __float2bfloat16(di * a1);
    bf16 b2 = __float2bfloat16(di * a2);
    bf16 b3 = __float2bfloat16(di * a3);
    ushort4 pk = make_ushort4(*(unsigned short*)&b0, *(unsigned short*)&b1,
                              *(unsigned short*)&b2, *(unsigned short*)&b3);
    *(ushort4*)((unsigned short*)u + (size_t)row * H + jq) = pk;
}

// ================= pipelined gather core (shared by both layers) =============
// R17 lane layout: b0 = j8 (channel octet: 8 bf16 = uint4 = 16B),
// b1 = p (node parity: 2 nodes per wave-iteration), b2..b5 = g (slot 0..15).
// Depth-2 pipeline (R13 shape): prefetch sorted for pair t+1 while consuming
// uv for pair t; uv for t+1 issued after the consume.
#define GATHER_TILE(UVPTR)                                                      \
    int lane = threadIdx.x & 63;                                                \
    int wave = threadIdx.x >> 6;                                                \
    int j8 = lane & 1, pp = (lane >> 1) & 1, g = lane >> 2;                     \
    int nodeBase = blockIdx.x * NPBLK + wave * NPW;                             \
    int r0c = 0, r1c = 0;                                                       \
    unsigned svc[PFD]; uint4 uvc[PFD];                                          \
    {   int node = nodeBase + pp;                                               \
        if (node < N) { r0c = rowptr[node]; r1c = rowptr[node + 1]; }           \
        _Pragma("unroll")                                                       \
        for (int m = 0; m < PFD; m++) {                                         \
            int k = r0c + g + 16 * m;                                           \
            if (k < r1c) svc[m] = sorted[k];                                    \
        }                                                                       \
        _Pragma("unroll")                                                       \
        for (int m = 0; m < PFD; m++) {                                         \
            int k = r0c + g + 16 * m;                                           \
            if (k < r1c) uvc[m] = UVPTR[(size_t)(svc[m] & 0x1FFFF) * 2 + j8];   \
        }                                                                       \
    }                                                                           \
    for (int t = 0; t < NPW / 2; t++) {                                         \
        int r0n = 0, r1n = 0;                                                   \
        unsigned svn[PFD];                                                      \
        if (t < NPW / 2 - 1) {                                                  \
            int nn = nodeBase + 2 * (t + 1) + pp;                               \
            if (nn < N) { r0n = rowptr[nn]; r1n = rowptr[nn + 1]; }             \
            _Pragma("unroll")                                                   \
            for (int m = 0; m < PFD; m++) {                                     \
                int k = r0n + g + 16 * m;                                       \
                if (k < r1n) svn[m] = sorted[k];                                \
            }                                                                   \
        }                                                                       \
        float a0=0.f,a1=0.f,a2=0.f,a3=0.f,a4=0.f,a5=0.f,a6=0.f,a7=0.f;          \
        _Pragma("unroll")                                                       \
        for (int m = 0; m < PFD; m++) {                                         \
            int k = r0c + g + 16 * m;                                           \
            if (k < r1c) {                                                      \
                a0 += bflo(uvc[m].x); a1 += bfhi(uvc[m].x);                     \
                a2 += bflo(uvc[m].y); a3 += bfhi(uvc[m].y);                     \
                a4 += bflo(uvc[m].z); a5 += bfhi(uvc[m].z);                     \
                a6 += bflo(uvc[m].w); a7 += bfhi(uvc[m].w);                     \
            }                                                                   \
        }                                                                       \
        for (int k = r0c + g + 16 * PFD; k < r1c; k += 16) {                    \
            uint4 va = UVPTR[(size_t)(sorted[k] & 0x1FFFF) * 2 + j8];           \
            a0 += bflo(va.x); a1 += bfhi(va.x);                                 \
            a2 += bflo(va.y); a3 += bfhi(va.y);                                 \
            a4 += bflo(va.z); a5 += bfhi(va.z);                                 \
            a6 += bflo(va.w); a7 += bfhi(va.w);                                 \
        }                                                                       \
        _Pragma("unroll")                                                       \
        for (int off = 4; off <= 32; off <<= 1) {                               \
            a0 += __shfl_xor(a0, off); a1 += __shfl_xor(a1, off);               \
            a2 += __shfl_xor(a2, off); a3 += __shfl_xor(a3, off);               \
            a4 += __shfl_xor(a4, off); a5 += __shfl_xor(a5, off);               \
            a6 += __shfl_xor(a6, off); a7 += __shfl_xor(a7, off);               \
        }                                                                       \
        if (g == 0) {                                                           \
            float* tp = &tile[(wave * NPW + 2 * t + pp) * 16 + 8 * j8];         \
            tp[0]=a0; tp[1]=a1; tp[2]=a2; tp[3]=a3;                             \
            tp[4]=a4; tp[5]=a5; tp[6]=a6; tp[7]=a7;                             \
        }                                                                       \
        if (t < NPW / 2 - 1) {                                                  \
            r0c = r0n; r1c = r1n;                                               \
            _Pragma("unroll")                                                   \
            for (int m = 0; m < PFD; m++) {                                     \
                int k = r0n + g + 16 * m;                                       \
                svc[m] = svn[m];                                                \
                if (k < r1n) uvc[m] = UVPTR[(size_t)(svn[m] & 0x1FFFF) * 2 + j8]; \
            }                                                                   \
        }                                                                       \
    }

// ---- layer-1 gather + finalize ----
__global__ void gatherfin1_kernel(const unsigned* __restrict__ sorted, const int* __restrict__ rowptr,
                                  const bf16* __restrict__ u, const float* __restrict__ dinv,
                                  const float* __restrict__ b1, const float* __restrict__ W2,
                                  bf16* __restrict__ u2, int N) {
    __shared__ float tile[NPBLK * 16];
    __shared__ float sW2[256];
    __shared__ float sb1[16];
    sW2[threadIdx.x] = W2[threadIdx.x];
    if (threadIdx.x < 16) sb1[threadIdx.x] = b1[threadIdx.x];

    const uint4* uvp = (const uint4*)u;   // [node*2 + j8] channel octets
    GATHER_TILE(uvp)
    __syncthreads();

    int jj = threadIdx.x & 15;
    for (int rr = 0; rr < NPBLK / 16; rr++) {
        int rl = (threadIdx.x >> 4) + rr * 16;
        int node = blockIdx.x * NPBLK + rl;
        float h = 0.f, di = 0.f;
        if (node < N) {
            di = dinv[node];
            h = di * (tile[rl * 16 + jj] + __bfloat162float(u[(size_t)node * H + jj])) + sb1[jj];
            h = fmaxf(h, 0.f);
        }
        float acc2 = 0.f;
#pragma unroll
        for (int kk = 0; kk < 16; kk++) {
            float hk = __shfl(h, kk, 16);
            acc2 += hk * sW2[kk * 16 + jj];
        }
        if (node < N) u2[(size_t)node * H + jj] = __float2bfloat16(di * acc2);
    }
}

// ---- layer-2 gather + finalize: log_softmax -> out (f32) ----
__global__ void gatherfin2_kernel(const unsigned* __restrict__ sorted, const int* __restrict__ rowptr,
                                  const bf16* __restrict__ u2, const float* __restrict__ dinv,
                                  const float* __restrict__ b2, float* __restrict__ out, int N) {
    __shared__ float tile[NPBLK * 16];
    __shared__ float sb2[16];
    if (threadIdx.x < 16) sb2[threadIdx.x] = b2[threadIdx.x];

    const uint4* uvp = (const uint4*)u2;
    GATHER_TILE(uvp)
    __syncthreads();

    int jj = threadIdx.x & 15;
    for (int rr = 0; rr < NPBLK / 16; rr++) {
        int rl = (threadIdx.x >> 4) + rr * 16;
        int node = blockIdx.x * NPBLK + rl;
        if (node >= N) continue;
        float di = dinv[node];
        float v = di * (tile[rl * 16 + jj] + __bfloat162float(u2[(size_t)node * H + jj])) + sb2[jj];

        float m = v;
#pragma unroll
        for (int off = 8; off >= 1; off >>= 1) m = fmaxf(m, __shfl_xor(m, off, 16));
        float ex = __expf(v - m);
        float s = ex;
#pragma unroll
        for (int off = 8; off >= 1; off >>= 1) s += __shfl_xor(s, off, 16);

        out[(size_t)node * H + jj] = v - m - __logf(s);
    }
}

extern "C" void kernel_launch(void* const* d_in, const int* in_sizes, int n_in,
                              void* d_out, int out_size, void* d_ws, size_t ws_size,
                              hipStream_t stream) {
    const float* x = (const float*)d_in[0];
    const int* edge_index = (const int*)d_in[1];
    const float* W1 = (const float*)d_in[2];
    const float* b1 = (const float*)d_in[3];
    const float* W2 = (const float*)d_in[4];
    const float* b2 = (const float*)d_in[5];
    float* out = (float*)d_out;

    const int N = in_sizes[0] / F_IN;        // 100000
    const int E = in_sizes[1] / 2;           // 3200000
    const int* src = edge_index;
    const int* dst = edge_index + E;

    // ws (4B units): dinv[N] | u[8N] | u2[8N] | sorted[E] | rowptr[N+1] |
    //                cur[N] | deg[N] | btot[128]
    float* dinv = (float*)d_ws;
    bf16* u = (bf16*)(dinv + N);
    bf16* u2 = (bf16*)((unsigned*)u + (size_t)N * H / 2);
    unsigned* sorted = (unsigned*)((unsigned*)u2 + (size_t)N * H / 2);
    int* rowptr = (int*)(sorted + E);
    int* cur = rowptr + N + 1;
    int* deg = cur + N;
    int* btot = deg + N;

    zero_kernel<<<(N + 255) / 256, 256, 0, stream>>>(deg, N);
    deg_kernel<<<3125, 256, 0, stream>>>(dst, deg, E);
    {
        int N_ = N, E_ = E;
        void* args[] = {(void*)&deg, (void*)&rowptr, (void*)&cur, (void*)&dinv,
                        (void*)&btot, (void*)&N_, (void*)&E_};
        hipLaunchCooperativeKernel((void*)scan_kernel, dim3(SCB), dim3(1024),
                                   args, 0, stream);
    }
    scatter_kernel<<<3125, 256, 0, stream>>>(src, dst, cur, sorted, E);

    xw1_kernel<<<(N + XR - 1) / XR, 256, 0, stream>>>(x, W1, dinv, u, N);
    gatherfin1_kernel<<<(N + NPBLK - 1) / NPBLK, 256, 0, stream>>>(sorted, rowptr, u, dinv, b1, W2, u2, N);
    gatherfin2_kernel<<<(N + NPBLK - 1) / NPBLK, 256, 0, stream>>>(sorted, rowptr, u2, dinv, b2, out, N);
}